// Round 4
// baseline (71.176 us; speedup 1.0000x reference)
//
#include <hip/hip_runtime.h>

// Problem constants (from reference):
//   left/right: [2, 32, 64, 128] f32, MAXDISP=192 -> D=48 coarse disparities
//   output: [2, 256, 512] f32 (soft-argmin disparity map)
#define BB 2
#define CC 32
#define HC 64
#define WC 128
#define DC 48
#define HO 256
#define WO 512
#define MAXD 192

// ---------------------------------------------------------------------------
// Kernel A: channel sums -> Ls[b][h][w], Rs[b][h][w]  (each 2*64*128 f32)
// 512 blocks x 256 threads; block -> (mat, b, h, w-half); sel = t>>6 sums 8
// channels (wave-uniform, coalesced over w), LDS-combine the 4 partials.
// ---------------------------------------------------------------------------
__global__ __launch_bounds__(256) void sum_channels_kernel(
    const float* __restrict__ left, const float* __restrict__ right,
    float* __restrict__ Ls, float* __restrict__ Rs) {
    __shared__ float sbuf[4][64];
    int blk = blockIdx.x;            // [0,512)
    int m   = blk >> 8;              // 0 = left, 1 = right
    int b   = (blk >> 7) & 1;
    int h   = (blk >> 1) & (HC - 1);
    int wh  = blk & 1;               // w half
    int t   = threadIdx.x;
    int sel = t >> 6;                // channel quarter (wave-uniform)
    int w   = wh * 64 + (t & 63);

    const float* src = (m ? right : left)
                     + (size_t)b * (CC * HC * WC)
                     + (size_t)(sel * 8) * (HC * WC) + h * WC + w;
    float s = 0.f;
#pragma unroll
    for (int c = 0; c < 8; ++c) s += src[c * (HC * WC)];
    sbuf[sel][t & 63] = s;
    __syncthreads();
    if (t < 64) {
        float* dst = m ? Rs : Ls;
        dst[b * (HC * WC) + h * WC + wh * 64 + t] =
            sbuf[0][t] + sbuf[1][t] + sbuf[2][t] + sbuf[3][t];
    }
}

// ---------------------------------------------------------------------------
// Kernel B: fused bilinear + cost-volume collapse + d-upsample + softmax +
// soft-argmin. dd range split 8 ways across the block's 8 waves.
// ---------------------------------------------------------------------------
template <int K>
__device__ inline void eighth_work(const float* __restrict__ Rh,
                                   int w0, int w1, float c0, float c1,
                                   float lw0, float lw1,
                                   float& plsum, float& pssum) {
    constexpr int DDLO = 24 * K;
    constexpr int DDHI = 24 * K + 23;
    constexpr int DLO  = (DDLO * (DC - 1)) / (MAXD - 1);   // floor
    constexpr int DHI  = (DDHI * (DC - 1)) / (MAXD - 1);
    constexpr int NV   = DHI - DLO + 2;                    // v[DLO .. DHI+1], <=8

    float vv[NV];
#pragma unroll
    for (int j = 0; j < NV; ++j) {
        int d = DLO + j;
        if (d > DC - 1) { vv[j] = vv[j - 1]; continue; }   // clamp v[48]->v[47]
        int i0 = w0 - d; float m0 = (i0 >= 0) ? 1.f : 0.f; i0 = max(i0, 0);
        int i1 = w1 - d; float m1 = (i1 >= 0) ? 1.f : 0.f; i1 = max(i1, 0);
        vv[j] = m0 * c0 * (lw0 + Rh[i0]) + m1 * c1 * (lw1 + Rh[i1]);
    }
    // 2x2 independent accumulator chains (fp adds are not reassociated by the
    // compiler; do it manually so exp->fma chains overlap)
    float ls0 = 0.f, ls1 = 0.f, ss0 = 0.f, ss1 = 0.f;
#pragma unroll
    for (int dd = DDLO; dd <= DDHI; ++dd) {
        int d    = (dd * (DC - 1)) / (MAXD - 1);           // compile-time fold
        float wd = (float)dd * (47.0f / 191.0f) - (float)d;
        float vc = vv[d - DLO];
        float x  = vc + wd * (vv[d - DLO + 1] - vc);
        float e  = __expf(x);                              // |x| small: no max shift
        if (dd & 1) { ls1 += e; ss1 += e * (float)dd; }
        else        { ls0 += e; ss0 += e * (float)dd; }
    }
    plsum = ls0 + ls1;
    pssum = ss0 + ss1;
}

__global__ __launch_bounds__(512, 8) void disparity_kernel(
    const float* __restrict__ Ls, const float* __restrict__ Rs,
    float* __restrict__ out) {
    __shared__ float Lh[WC];
    __shared__ float Rh[WC];
    __shared__ float redL[8][64];
    __shared__ float redS[8][64];

    int blk = blockIdx.x;            // [0, 4096)
    int r   = blk >> 3;              // output row [0, BB*HO)
    int g   = blk & 7;               // 64-pixel column group
    int b   = r >> 8;
    int hh  = r & (HO - 1);

    float src_h = (float)hh * (63.0f / 255.0f);
    int h0 = (int)src_h; if (h0 > HC - 1) h0 = HC - 1;
    int h1 = min(h0 + 1, HC - 1);
    float fh = src_h - (float)h0;

    int t = threadIdx.x;

    // Phase 1: load + fh-blend the two coarse rows (L2-resident, coalesced)
    if (t < WC) {
        const float* p = Ls + b * (HC * WC) + t;
        Lh[t] = (1.f - fh) * p[h0 * WC] + fh * p[h1 * WC];
    } else if (t < 2 * WC) {
        int u = t - WC;
        const float* p = Rs + b * (HC * WC) + u;
        Rh[u] = (1.f - fh) * p[h0 * WC] + fh * p[h1 * WC];
    }
    __syncthreads();

    // Phase 2: per-pixel eighth of the dd range. k = t>>6 is wave-uniform.
    int p = t & 63;                  // pixel within group
    int k = t >> 6;                  // dd eighth
    int ww = g * 64 + p;

    float src_w = (float)ww * (127.0f / 511.0f);
    int w0 = (int)src_w; if (w0 > WC - 1) w0 = WC - 1;
    int w1 = min(w0 + 1, WC - 1);
    float fw = src_w - (float)w0;

    const float scale = 1.0f / 64.0f;    // mean over 2C = 64 channels
    float c0 = (1.f - fw) * scale;
    float c1 = fw * scale;
    float lw0 = Lh[w0];
    float lw1 = Lh[w1];

    float pls, pss;
    switch (k) {                      // wave-uniform branch, no divergence
        case 0: eighth_work<0>(Rh, w0, w1, c0, c1, lw0, lw1, pls, pss); break;
        case 1: eighth_work<1>(Rh, w0, w1, c0, c1, lw0, lw1, pls, pss); break;
        case 2: eighth_work<2>(Rh, w0, w1, c0, c1, lw0, lw1, pls, pss); break;
        case 3: eighth_work<3>(Rh, w0, w1, c0, c1, lw0, lw1, pls, pss); break;
        case 4: eighth_work<4>(Rh, w0, w1, c0, c1, lw0, lw1, pls, pss); break;
        case 5: eighth_work<5>(Rh, w0, w1, c0, c1, lw0, lw1, pls, pss); break;
        case 6: eighth_work<6>(Rh, w0, w1, c0, c1, lw0, lw1, pls, pss); break;
        default: eighth_work<7>(Rh, w0, w1, c0, c1, lw0, lw1, pls, pss); break;
    }
    redL[k][p] = pls;
    redS[k][p] = pss;
    __syncthreads();

    // Phase 3: combine eighths, soft-argmin, coalesced store
    if (t < 64) {
        float ls = 0.f, ss = 0.f;
#pragma unroll
        for (int q = 0; q < 8; ++q) { ls += redL[q][t]; ss += redS[q][t]; }
        out[r * WO + g * 64 + t] = ss / ls;
    }
}

extern "C" void kernel_launch(void* const* d_in, const int* in_sizes, int n_in,
                              void* d_out, int out_size, void* d_ws, size_t ws_size,
                              hipStream_t stream) {
    const float* left  = (const float*)d_in[0];
    const float* right = (const float*)d_in[1];
    float* out = (float*)d_out;
    float* Ls  = (float*)d_ws;                 // BB*HC*WC floats
    float* Rs  = Ls + BB * HC * WC;            // BB*HC*WC floats

    sum_channels_kernel<<<512, 256, 0, stream>>>(left, right, Ls, Rs);
    disparity_kernel<<<BB * HO * 8, 512, 0, stream>>>(Ls, Rs, out);
}